// Round 4
// baseline (926.034 us; speedup 1.0000x reference)
//
#include <hip/hip_runtime.h>
#include <stdint.h>

#define HMAP_MASK ((1u << 19) - 1u)

typedef float f32x4_t __attribute__((ext_vector_type(4)));

// ============================================================================
// XCD-partitioned 3-kernel design, round 3 (resubmit after infra failure).
//
// R2 finding: gather is pinned at the per-XCD L2 request service rate
// (134M 8B gathers / 8 XCDs / ~16 req/cy/XCD = 437us ~= 471us measured).
// R3 levers:
//  (a) corner pairing: when p0 is even, the two x-corners are table entries
//      {idx0, idx0^1} for BOTH dense (idx even, +1) and hashed (P0=1 so
//      (px+1)^h = idx0^1) indexing -> one aligned float4 load replaces two
//      float2 loads. Avg requests/thread 8 -> 6.
//  (b) balanced slice->XCD map: table = s&3, level = s>>2 gives every XCD
//      exactly 1 dense + 7 hashed slices (before: XCD2-7 had 8 hashed each).
//  (c) float4-vectorized transpose.
// Arithmetic identical to the verified kernel (contract off, same op order,
// same accumulation order) -> bit-exact.
// ============================================================================

__global__ __launch_bounds__(256) void u_precompute_kernel(
    const float4* __restrict__ coords,
    const float4* __restrict__ refc,
    float4* __restrict__ uout, int npts)
{
    #pragma clang fp contract(off)
    int p = blockIdx.x * 256 + threadIdx.x;
    if (p >= npts) return;
    float4 c = coords[p];
    float4 r = refc[p];
    float rx = c.x - r.x, ry = c.y - r.y, rz = c.z - r.z, rt = c.w - r.w;
    const float R180   = 1.0f / 180.0f;    // XLA div->recip-mul canonicalization
    const float R360   = 1.0f / 360.0f;
    const float R20000 = 1.0f / 20000.0f;
    float x = fminf(fmaxf((rx + 90.0f)    * R180,   0.0f), 1.0f);
    float y = fminf(fmaxf((ry + 180.0f)   * R360,   0.0f), 1.0f);
    float z = fminf(fmaxf((rz + 11000.0f) * R20000, 0.0f), 1.0f);
    float tt = fminf(fmaxf(rt, 0.0f), 1.0f);
    float ts = (tt * 2.0f - 1.0f) * 0.9f;
    uout[p] = make_float4(x, y, z, ts);
}

__global__ __launch_bounds__(256) void gather_kernel(
    const float4* __restrict__ u,
    const float2* __restrict__ t0,
    const float2* __restrict__ t1,
    const float2* __restrict__ t2,
    const float2* __restrict__ t3,
    float2* __restrict__ stage, int npts, int chunks)
{
    #pragma clang fp contract(off)
    int bid = blockIdx.x;
    int xcd   = bid & 7;            // round-robin blockIdx -> XCD
    int j     = bid >> 3;
    int phase = j / chunks;         // 0..7: this XCD's phase
    int chunk = j - phase * chunks;
    int s     = phase * 8 + xcd;    // slice id; slices s==xcd (mod 8) per XCD
    // balanced decode: each XCD gets 1 dense + 7 hashed levels, one table
    int table_id = s & 3;           // wave-uniform
    int level    = s >> 2;          // XCD k<4: levels {0,2,..14}; k>=4: {1,..15}
    int sub_out  = table_id * 16 + level;   // row in stage == final sub index

    int point = chunk * 256 + threadIdx.x;
    if (point >= npts) return;

    float4 uu = u[point];
    // dim selection per table: t0=(x,y,z) t1=(x,y,ts) t2=(y,z,ts) t3=(x,z,ts)
    float d0 = (table_id == 2) ? uu.y : uu.x;
    float d1 = (table_id <= 1) ? uu.y : uu.z;
    float d2 = (table_id == 0) ? uu.z : uu.w;
    const float2* tab = (table_id == 0) ? t0
                      : (table_id == 1) ? t1
                      : (table_id == 2) ? t2 : t3;

    // hash_encode: u = clip((d+1)/2, 0, 1); /2 exact as *0.5
    float u0 = fminf(fmaxf((d0 + 1.0f) * 0.5f, 0.0f), 1.0f);
    float u1 = fminf(fmaxf((d1 + 1.0f) * 0.5f, 0.0f), 1.0f);
    float u2 = fminf(fmaxf((d2 + 1.0f) * 0.5f, 0.0f), 1.0f);

    int res = 32 << level;                 // ceil(32*2^l) exact
    float resm1 = (float)(res - 1);
    float pos0 = u0 * resm1;
    float pos1 = u1 * resm1;
    float pos2 = u2 * resm1;
    int p0 = min(max((int)floorf(pos0), 0), res - 2);
    int p1 = min(max((int)floorf(pos1), 0), res - 2);
    int p2 = min(max((int)floorf(pos2), 0), res - 2);
    float w0 = pos0 - (float)p0;   // contract(off): uses rounded pos
    float w1 = pos1 - (float)p1;
    float w2 = pos2 - (float)p2;

    // level offsets: l0->0 (dense 32^3), l1->32768 (dense 64^3),
    // l>=2 -> 294912 + (l-2)*524288 (hashed)
    int off = (level >= 2) ? (294912 + ((level - 2) << 19)) : (level << 15);
    bool use_hash = (level >= 2);
    const float2* tabo = tab + off;

    float om0 = 1.0f - w0, om1 = 1.0f - w1, om2 = 1.0f - w2;
    float a0 = 0.0f, a1 = 0.0f;
    uint32_t ures = (uint32_t)res;
    uint32_t px0 = (uint32_t)p0;

    if ((p0 & 1) == 0) {
        // even p0: x-corner pair = entries {idx0, idx0^1} -> one float4 load.
        // Accumulation order = corner order ci=0..7 (cx fastest), exact.
        #pragma unroll
        for (int cj = 0; cj < 4; ++cj) {
            int cy = cj & 1, cz = (cj >> 1) & 1;
            uint32_t py = (uint32_t)(p1 + cy);
            uint32_t pz = (uint32_t)(p2 + cz);
            uint32_t idx0;
            if (use_hash) {
                idx0 = (px0 ^ (py * 2654435761u) ^ (pz * 805459861u)) & HMAP_MASK;
            } else {
                idx0 = px0 + ures * (py + ures * pz);
            }
            float4 qv = *reinterpret_cast<const float4*>(tabo + (idx0 & ~1u));
            bool hi0 = (idx0 & 1u) != 0u;     // entry idx0 in hi half?
            float f0x = hi0 ? qv.z : qv.x, f0y = hi0 ? qv.w : qv.y;
            float f1x = hi0 ? qv.x : qv.z, f1y = hi0 ? qv.y : qv.w;
            float wy = cy ? w1 : om1;
            float wz = cz ? w2 : om2;
            float ww0 = (om0 * wy) * wz;      // ((wx*wy)*wz), same assoc
            float ww1 = (w0  * wy) * wz;
            a0 += f0x * ww0; a1 += f0y * ww0; // cx=0 first, then cx=1
            a0 += f1x * ww1; a1 += f1y * ww1;
        }
    } else {
        #pragma unroll
        for (int ci = 0; ci < 8; ++ci) {
            int cx = ci & 1, cy = (ci >> 1) & 1, cz = (ci >> 2) & 1;
            uint32_t px = (uint32_t)(p0 + cx);
            uint32_t py = (uint32_t)(p1 + cy);
            uint32_t pz = (uint32_t)(p2 + cz);
            uint32_t idx;
            if (use_hash) {
                idx = (px ^ (py * 2654435761u) ^ (pz * 805459861u)) & HMAP_MASK;
            } else {
                idx = px + ures * (py + ures * pz);
            }
            float2 f = tabo[idx];
            float ww = (cx ? w0 : om0) * (cy ? w1 : om1) * (cz ? w2 : om2);
            a0 += f.x * ww;
            a1 += f.y * ww;
        }
    }

    // slice-major staging: wave writes 512B contiguous; nontemporal (write-
    // once stream, keep table lines resident in L2).
    float2 val = make_float2(a0, a1);
    unsigned long long bits;
    __builtin_memcpy(&bits, &val, 8);
    __builtin_nontemporal_store(bits,
        (unsigned long long*)(stage + (size_t)sub_out * npts + point));
}

__global__ __launch_bounds__(256) void transpose_kernel(
    const float2* __restrict__ stage,
    float2* __restrict__ out, int npts)
{
    __shared__ float2 tile[64][66];   // 66: even (float4-aligned rows) + pad
    int pbase = blockIdx.x * 64;
    int tid = threadIdx.x;

    if (pbase + 64 <= npts) {
        // load: float4 = 2 points of one sub row
        int l = tid & 31, r = tid >> 5;           // r in 0..7
        #pragma unroll
        for (int i = 0; i < 8; ++i) {
            int sub = i * 8 + r;
            float4 v = *reinterpret_cast<const float4*>(
                stage + (size_t)sub * npts + pbase + 2 * l);
            *reinterpret_cast<float4*>(&tile[sub][2 * l]) = v;
        }
        __syncthreads();
        // store: thread owns point p = tid>>2, sub-quad q = tid&3 (16 subs)
        int p = tid >> 2, q = tid & 3;
        float2* orow = out + (size_t)(pbase + p) * 64;
        #pragma unroll
        for (int i = 0; i < 8; ++i) {
            int sub = q * 16 + 2 * i;
            float2 e0 = tile[sub][p];
            float2 e1 = tile[sub + 1][p];
            f32x4_t v;
            v[0] = e0.x; v[1] = e0.y; v[2] = e1.x; v[3] = e1.y;
            __builtin_nontemporal_store(v, (f32x4_t*)(orow + sub));
        }
    } else {
        // tail (unused for npts % 64 == 0), scalar guarded path
        int lane = tid & 63;
        int row4 = tid >> 6;
        #pragma unroll
        for (int ss = 0; ss < 64; ss += 4) {
            int sub = ss + row4;
            int p = pbase + lane;
            if (p < npts)
                tile[sub][lane] = stage[(size_t)sub * npts + p];
        }
        __syncthreads();
        #pragma unroll
        for (int p4 = 0; p4 < 64; p4 += 4) {
            int p = pbase + p4 + row4;
            if (p < npts) {
                float2 v = tile[lane][p4 + row4];
                unsigned long long bits;
                __builtin_memcpy(&bits, &v, 8);
                __builtin_nontemporal_store(bits,
                    (unsigned long long*)(out + (size_t)p * 64 + lane));
            }
        }
    }
}

// ---------------- fallback (round-1 kernel) if workspace is too small -------
__global__ __launch_bounds__(256) void energy4d_fallback(
    const float4* __restrict__ coords,
    const float4* __restrict__ refc,
    const float2* __restrict__ t0,
    const float2* __restrict__ t1,
    const float2* __restrict__ t2,
    const float2* __restrict__ t3,
    float2* __restrict__ out, int npts)
{
    #pragma clang fp contract(off)
    int t = threadIdx.x;
    int si = t & 7;
    int pi = t >> 3;
    int point = blockIdx.x * 32 + pi;
    if (point >= npts) return;
    int sub = (blockIdx.y << 3) + si;
    int table_id = sub >> 4;
    int level = sub & 15;

    float4 c = coords[point];
    float4 r = refc[point];
    float rx = c.x - r.x, ry = c.y - r.y, rz = c.z - r.z, rt = c.w - r.w;
    const float R180   = 1.0f / 180.0f;
    const float R360   = 1.0f / 360.0f;
    const float R20000 = 1.0f / 20000.0f;
    float x = fminf(fmaxf((rx + 90.0f)    * R180,   0.0f), 1.0f);
    float y = fminf(fmaxf((ry + 180.0f)   * R360,   0.0f), 1.0f);
    float z = fminf(fmaxf((rz + 11000.0f) * R20000, 0.0f), 1.0f);
    float tt = fminf(fmaxf(rt, 0.0f), 1.0f);
    float ts = (tt * 2.0f - 1.0f) * 0.9f;

    float d0 = (table_id == 2) ? y : x;
    float d1 = (table_id <= 1) ? y : z;
    float d2 = (table_id == 0) ? z : ts;
    const float2* tab = (table_id == 0) ? t0
                      : (table_id == 1) ? t1
                      : (table_id == 2) ? t2 : t3;

    float u0 = fminf(fmaxf((d0 + 1.0f) * 0.5f, 0.0f), 1.0f);
    float u1 = fminf(fmaxf((d1 + 1.0f) * 0.5f, 0.0f), 1.0f);
    float u2 = fminf(fmaxf((d2 + 1.0f) * 0.5f, 0.0f), 1.0f);

    int res = 32 << level;
    float resm1 = (float)(res - 1);
    float pos0 = u0 * resm1;
    float pos1 = u1 * resm1;
    float pos2 = u2 * resm1;
    int p0 = min(max((int)floorf(pos0), 0), res - 2);
    int p1 = min(max((int)floorf(pos1), 0), res - 2);
    int p2 = min(max((int)floorf(pos2), 0), res - 2);
    float w0 = pos0 - (float)p0;
    float w1 = pos1 - (float)p1;
    float w2 = pos2 - (float)p2;

    int off = (level >= 2) ? (294912 + ((level - 2) << 19)) : (level << 15);
    bool use_hash = (level >= 2);
    const float2* tabo = tab + off;

    float om0 = 1.0f - w0, om1 = 1.0f - w1, om2 = 1.0f - w2;
    float a0 = 0.0f, a1 = 0.0f;
    uint32_t ures = (uint32_t)res;

    #pragma unroll
    for (int ci = 0; ci < 8; ++ci) {
        int cx = ci & 1, cy = (ci >> 1) & 1, cz = (ci >> 2) & 1;
        uint32_t px = (uint32_t)(p0 + cx);
        uint32_t py = (uint32_t)(p1 + cy);
        uint32_t pz = (uint32_t)(p2 + cz);
        uint32_t idx;
        if (use_hash) {
            idx = (px ^ (py * 2654435761u) ^ (pz * 805459861u)) & HMAP_MASK;
        } else {
            idx = px + ures * (py + ures * pz);
        }
        float2 f = tabo[idx];
        float ww = (cx ? w0 : om0) * (cy ? w1 : om1) * (cz ? w2 : om2);
        a0 += f.x * ww;
        a1 += f.y * ww;
    }

    float2 val = make_float2(a0, a1);
    unsigned long long bits;
    __builtin_memcpy(&bits, &val, 8);
    __builtin_nontemporal_store(bits,
        (unsigned long long*)(out + (size_t)point * 64 + sub));
}

extern "C" void kernel_launch(void* const* d_in, const int* in_sizes, int n_in,
                              void* d_out, int out_size, void* d_ws, size_t ws_size,
                              hipStream_t stream) {
    const float4* coords = (const float4*)d_in[0];
    const float4* refc   = (const float4*)d_in[1];
    const float2* t0 = (const float2*)d_in[2];
    const float2* t1 = (const float2*)d_in[3];
    const float2* t2 = (const float2*)d_in[4];
    const float2* t3 = (const float2*)d_in[5];
    float2* out = (float2*)d_out;
    int npts = in_sizes[0] / 4;

    size_t u_bytes     = (size_t)npts * 16;       // float4 per point
    size_t stage_bytes = (size_t)npts * 64 * 8;   // float2 per (slice,point)
    size_t needed = u_bytes + stage_bytes;

    if (d_ws != nullptr && ws_size >= needed) {
        float4* uws   = (float4*)d_ws;
        float2* stage = (float2*)((char*)d_ws + u_bytes);
        int chunks = (npts + 255) / 256;

        u_precompute_kernel<<<chunks, 256, 0, stream>>>(coords, refc, uws, npts);
        gather_kernel<<<64 * chunks, 256, 0, stream>>>(
            uws, t0, t1, t2, t3, stage, npts, chunks);
        transpose_kernel<<<(npts + 63) / 64, 256, 0, stream>>>(stage, out, npts);
    } else {
        int grid_x = (npts + 31) / 32;
        dim3 grid(grid_x, 8);
        energy4d_fallback<<<grid, 256, 0, stream>>>(coords, refc, t0, t1, t2, t3,
                                                    out, npts);
    }
}